// Round 16
// baseline (56.866 us; speedup 1.0000x reference)
//
#include <hip/hip_runtime.h>

#define HH    1024
#define WW    1024
#define KS    15
#define PAD   7
#define CELL  256
#define BX    64            // x-width per block (4 waves x 16)
#define TROWS 142           // tile rows (128-row strip + 2*PAD)
#define TCOLS 80            // staged halves per row (160B rows)
#define NSUP  8             // super-iters: 2 strips x 4 (each = 2 patches = 32 rows)
#define CHN   10            // 2 strips x 5 chunks (4 x 32 rows + 14-row tail)
#define AWS_CELL_BYTES (KS * 1024)   // 15 fragments x 1KB

typedef _Float16     f16x8 __attribute__((ext_vector_type(8)));
typedef _Float16     f16x4 __attribute__((ext_vector_type(4)));
typedef float        f32x4 __attribute__((ext_vector_type(4)));
typedef unsigned int u32x4 __attribute__((ext_vector_type(4)));

// Barrier with LDS ordering only (no vmcnt(0) drain): output stores and
// prefetch loads ride across; ds_write data dependency gives precise vmcnt.
static __device__ __forceinline__ void light_barrier() {
    asm volatile("s_waitcnt lgkmcnt(0)\n\ts_barrier" ::: "memory");
}

// ---- prep: materialize normalized Toeplitz A fragments per cell into d_ws ----
__global__ __launch_bounds__(256) void pb_prep_kernel(
    const float* __restrict__ kern, unsigned int* __restrict__ aws)
{
    const int cell = blockIdx.x;           // cj*4+ci
    const int tid  = threadIdx.x;
    const int lane = tid & 63;
    const float* kp = kern + cell * (KS * KS);

    float s = 0.f;
    #pragma unroll
    for (int i = 0; i < 4; ++i) {
        int t = lane + 64 * i;
        s += (t < KS * KS) ? kp[t] : 0.f;
    }
    #pragma unroll
    for (int m = 1; m < 64; m <<= 1) s += __shfl_xor(s, m, 64);
    const float inv = 1.0f / (s + 1e-12f);

    const int i  = tid >> 4;               // x-position (A row)
    const int k2 = tid & 15;               // half-pair index
    unsigned int* wp = aws + cell * (AWS_CELL_BYTES / 4) + tid;

    for (int dy = 0; dy < KS; ++dy) {
        float v0 = 0.f, v1 = 0.f;
        int dx0 = 2 * k2 - i - 1;          // A[i][k] = kh[k-i-1]
        int dx1 = dx0 + 1;
        if (dx0 >= 0 && dx0 < KS) v0 = kp[dy * KS + dx0] * inv;
        if (dx1 >= 0 && dx1 < KS) v1 = kp[dy * KS + dx1] * inv;
        f16x4 h; h[0] = (_Float16)v0; h[1] = (_Float16)v1; h[2] = 0; h[3] = 0;
        unsigned long long u = __builtin_bit_cast(unsigned long long, h);
        wp[dy * 256] = (unsigned int)u;
    }
}

// ---- main: 256-row rolling block (R15) with DUAL-PATCH super-iterations.
// Per super-iter: 2 patches (32 rows), 4 independent acc chains, 30 ds_reads
// between barriers; 9 barriers/block vs R15's 17. 32-row staging chunks
// (<=3 float4/thread in flight per chunk). Static issue/write tables,
// compile-time slot indices (no scratch). Disjointness verified per iter.
__global__ __launch_bounds__(256, 3) void pb_mfma_kernel(
    const float* __restrict__ x,
    const unsigned int* __restrict__ aws,
    float* __restrict__ out)
{
    __shared__ __align__(16) _Float16 s_tile[TROWS * TCOLS];   // 22720 B

    const int tid  = threadIdx.x;
    const int lane = tid & 63;
    const int w    = tid >> 6;           // wave id: x sub-block
    const int g    = lane >> 4;          // k-group 0..3
    const int cc   = lane & 15;          // A-row / B-col index

    const int bx0 = blockIdx.x * BX;
    const int ci  = blockIdx.x >> 2;     // cell col
    const int cj  = blockIdx.y;          // cell row
    const int bc  = blockIdx.z;          // plane (b*c)

    const int cellx0 = ci * CELL;
    const int celly0 = cj * CELL, celly1 = celly0 + CELL - 1;

    const float* plane = x + (size_t)bc * HH * WW;

    // ---- A fragments: 15 coalesced dwordx4 loads, pinned resident (R8) ----
    const u32x4* ap = (const u32x4*)(aws + (cj * 4 + ci) * (AWS_CELL_BYTES / 4))
                      + cc * 4 + g;
    u32x4 af[KS];
    #pragma unroll
    for (int dy = 0; dy < KS; ++dy) af[dy] = ap[dy * 64];
    #pragma unroll
    for (int dy = 0; dy < KS; ++dy) asm volatile("" : "+v"(af[dy]));

    // ---- staging helpers: 32-row chunks (640 groups; tail 280) ----
    // chunk c: strip = c/5, lc = c%5; tile rows lc*32 .. lc*32+31 (lc=4: +13).
    auto stage_addr = [&](int strip, int lc, int idx) -> const float* {
        int r20  = idx / 20;
        int c4   = idx - r20 * 20;
        int row  = lc * 32 + r20;                       // tile row 0..141
        int gy   = min(max(celly0 + strip * 128 - PAD + row, celly0), celly1);
        int gx0  = bx0 - 8 + 4 * c4;
        int gx0c = min(max(gx0, cellx0), cellx0 + CELL - 4);
        return plane + (size_t)gy * WW + gx0c;
    };
    auto write_group = [&](int lc, int idx, float4 v) {
        int r20 = idx / 20;
        int c4  = idx - r20 * 20;
        int row = lc * 32 + r20;
        int gx0 = bx0 - 8 + 4 * c4;
        bool lo = gx0 <  cellx0;
        bool hi = gx0 >  cellx0 + CELL - 4;
        float e0 = hi ? v.w : v.x;
        float e1 = lo ? v.x : (hi ? v.w : v.y);
        float e2 = lo ? v.x : (hi ? v.w : v.z);
        float e3 = lo ? v.x : v.w;
        f16x4 h;
        h[0] = (_Float16)e0; h[1] = (_Float16)e1;
        h[2] = (_Float16)e2; h[3] = (_Float16)e3;
        *(f16x4*)(s_tile + row * TCOLS + 4 * c4) = h;   // ds_write_b64
    };

    // pending slots, indexed by (chunk & 3) — compile-time after unroll
    float4 pa[4], pb[4], pc[4];
    bool   h1[4], h2[4];

    auto issue_chunk = [&](int c) {
        int strip = c >= 5;
        int lc    = c - 5 * strip;
        int ng    = (lc == 4) ? 280 : 640;
        int s     = c & 3;
        pa[s] = *(const float4*)stage_addr(strip, lc, tid);
        h1[s] = 256 + tid < ng;
        h2[s] = 512 + tid < ng;
        if (h1[s]) pb[s] = *(const float4*)stage_addr(strip, lc, 256 + tid);
        if (h2[s]) pc[s] = *(const float4*)stage_addr(strip, lc, 512 + tid);
    };
    auto write_chunk = [&](int c) {
        int strip = c >= 5;
        int lc    = c - 5 * strip;
        int s     = c & 3;
        (void)strip;
        write_group(lc, tid, pa[s]);
        if (h1[s]) write_group(lc, 256 + tid, pb[s]);
        if (h2[s]) write_group(lc, 512 + tid, pc[s]);
    };

    // ---- prologue: stage chunks 0,1; issue 2,3 pending ----
    issue_chunk(0); write_chunk(0);
    issue_chunk(1); write_chunk(1);
    issue_chunk(2);
    issue_chunk(3);
    light_barrier();

    // ---- static schedules (verified: every chunk written >=1 iter before
    // first read; every write disjoint from concurrent reads) ----
    static constexpr int ISS[NSUP][2] = {{4,-1},{5,-1},{6,7},{8,-1},{9,-1},{-1,-1},{-1,-1},{-1,-1}};
    static constexpr int WRT[NSUP][2] = {{2,-1},{3,-1},{4,-1},{5,6},{7,-1},{8,-1},{9,-1},{-1,-1}};

    const _Float16* bbase = s_tile + cc * TCOLS + w * 16 + g * 8;
    float* oplane = out + (size_t)bc * HH * WW;

    #pragma unroll
    for (int t = 0; t < NSUP; ++t) {
        const int strip = t >> 2;
        const int tl    = t & 3;
        const int jpl0  = 2 * tl;
        const int jpl1  = 2 * tl + 1;

        // issue this iter's chunks (written 1-2 iters later)
        if (ISS[t][0] >= 0) issue_chunk(ISS[t][0]);
        if (ISS[t][1] >= 0) issue_chunk(ISS[t][1]);

        // dual-patch compute: 4 independent MFMA chains
        f32x4 a00 = {0,0,0,0}, a01 = {0,0,0,0};   // patch jpl0, even/odd dy
        f32x4 a10 = {0,0,0,0}, a11 = {0,0,0,0};   // patch jpl1
        #pragma unroll
        for (int dy = 0; dy < KS; ++dy) {
            f16x8 b0 = *(const f16x8*)(bbase + (16 * jpl0 + dy) * TCOLS);
            f16x8 b1 = *(const f16x8*)(bbase + (16 * jpl1 + dy) * TCOLS);
            f16x8 a  = __builtin_bit_cast(f16x8, af[dy]);
            if (dy & 1) {
                a01 = __builtin_amdgcn_mfma_f32_16x16x32_f16(a, b0, a01, 0, 0, 0);
                a11 = __builtin_amdgcn_mfma_f32_16x16x32_f16(a, b1, a11, 0, 0, 0);
            } else {
                a00 = __builtin_amdgcn_mfma_f32_16x16x32_f16(a, b0, a00, 0, 0, 0);
                a10 = __builtin_amdgcn_mfma_f32_16x16x32_f16(a, b1, a10, 0, 0, 0);
            }
        }
        f32x4 r0 = a00 + a01;
        f32x4 r1 = a10 + a11;
        // D: col=lane&15 (image row), row=4*(lane>>4)+e (x position)
        {
            float* op0 = oplane
                + (size_t)(celly0 + strip * 128 + 16 * jpl0 + cc) * WW
                + bx0 + 16 * w + 4 * g;
            float* op1 = oplane
                + (size_t)(celly0 + strip * 128 + 16 * jpl1 + cc) * WW
                + bx0 + 16 * w + 4 * g;
            *(f32x4*)op0 = r0;   // rides across light barriers, no drain
            *(f32x4*)op1 = r1;
        }

        // land pending chunks (tile rows disjoint from this iter's reads)
        if (WRT[t][0] >= 0) write_chunk(WRT[t][0]);
        if (WRT[t][1] >= 0) write_chunk(WRT[t][1]);
        light_barrier();
    }
}

extern "C" void kernel_launch(void* const* d_in, const int* in_sizes, int n_in,
                              void* d_out, int out_size, void* d_ws, size_t ws_size,
                              hipStream_t stream) {
    (void)in_sizes; (void)n_in; (void)ws_size; (void)out_size;
    const float* x    = (const float*)d_in[0];
    const float* kern = (const float*)d_in[1];
    float* out        = (float*)d_out;
    unsigned int* aws = (unsigned int*)d_ws;   // 16 cells x 15 KiB = 240 KiB

    pb_prep_kernel<<<16, 256, 0, stream>>>(kern, aws);
    dim3 grid(WW / BX, 4, 8 * 3);   // 16 x-strips, 4 cell-rows, 24 planes
    pb_mfma_kernel<<<grid, 256, 0, stream>>>(x, aws, out);
}